// Round 2
// baseline (153.107 us; speedup 1.0000x reference)
//
#include <hip/hip_runtime.h>

// NeuralOoOScheduler: B=8192, W=64. Embedding path in the reference is dead
// (del emb) — only the hazard dep_matrix + readiness are live.
// Pure streaming-write kernel: 134 MB dep + 2 MB ready out, 2 MB in.
//
// Wave-autonomous (no __syncthreads, no LDS). Each 64-lane wave owns one b.
// Column (j) operands and row (i) broadcasts come from __shfl of the raw
// instruction word; readiness reduced via __shfl_xor. Stores are nontemporal
// 16B vector stores (1 KiB contiguous per wave-store), so the kernel is an
// uninterrupted store stream like the 6.5 TB/s fill kernel.

constexpr int Bv = 8192;
constexpr int Wv = 64;

// __builtin_nontemporal_store needs a clang-native vector type, not HIP's
// HIP_vector_type struct.
typedef float fv4 __attribute__((ext_vector_type(4)));

__global__ __launch_bounds__(256) void ooo_kernel(
    const int* __restrict__ inst,
    const float* __restrict__ hw,
    float* __restrict__ dep,
    float* __restrict__ ready)
{
    const int lane  = threadIdx.x & 63;
    const int wid   = threadIdx.x >> 6;          // wave within block (0..3)
    const int wave0 = blockIdx.x * 4 + wid;      // global wave id
    const int nw    = gridDim.x * 4;

    // score = h0*raw + h2*waw + h4 -> only 4 distinct sigmoid values
    const float h0 = hw[0], h2 = hw[2], h4 = hw[4];
    const float v00 = 1.f / (1.f + __expf(-(h4)));            // raw=0 waw=0
    const float v10 = 1.f / (1.f + __expf(-(h0 + h4)));       // raw=1 waw=0
    const float v01 = 1.f / (1.f + __expf(-(h2 + h4)));       // raw=0 waw=1
    const float v11 = 1.f / (1.f + __expf(-(h0 + h2 + h4)));  // raw=1 waw=1

    // lane -> j in [jb, jb+4), i in {ig + 4k}; one wave-store per k covers
    // rows 4k..4k+3 = 1 KiB contiguous.
    const int jb = (lane & 15) << 2;
    const int ig = lane >> 4;

    for (int b = wave0; b < Bv; b += nw) {
        const int v = inst[(size_t)b * Wv + lane];   // lane l holds inst[l]

        // column-j operands for this lane's j-quad, via wave shuffles
        int  rdj[4], rnj[4], rmj[4];
        bool jv[4];
#pragma unroll
        for (int q = 0; q < 4; ++q) {
            const int vj = __shfl(v, jb + q);
            rdj[q] = vj & 31;
            rnj[q] = (vj >> 5) & 31;
            rmj[q] = (vj >> 16) & 31;
            jv[q]  = rdj[q] < 31;
        }

        float prod[4] = {1.f, 1.f, 1.f, 1.f};
        float* const dep_row = dep + (size_t)b * (Wv * Wv);

#pragma unroll
        for (int k = 0; k < 16; ++k) {
            const int  i   = ig + 4 * k;
            const int  vi  = __shfl(v, i);      // broadcast row i's instruction
            const int  rdi = vi & 31;
            const bool iv  = rdi < 31;
            fv4 o;
#pragma unroll
            for (int q = 0; q < 4; ++q) {
                const int  j   = jb + q;
                const bool raw = iv && ((rdi == rnj[q]) || (rdi == rmj[q]));
                const bool waw = iv && jv[q] && (rdi == rdj[q]);
                float val = waw ? (raw ? v11 : v01) : (raw ? v10 : v00);
                float d   = (j > i) ? val : 0.f;
                o[q] = d;
                prod[q] *= (1.f - d);
            }
            __builtin_nontemporal_store(o, (fv4*)(dep_row + i * Wv + jb));
        }

        // readiness[j] = product over the 4 lanes (ig=0..3) sharing this j-quad
#pragma unroll
        for (int q = 0; q < 4; ++q) {
            prod[q] *= __shfl_xor(prod[q], 16);
            prod[q] *= __shfl_xor(prod[q], 32);
        }
        if (ig == 0) {  // lanes 0..15 store 4 floats each -> 256 B contiguous
            fv4 r = {prod[0], prod[1], prod[2], prod[3]};
            __builtin_nontemporal_store(r, (fv4*)(ready + (size_t)b * Wv + jb));
        }
    }
}

extern "C" void kernel_launch(void* const* d_in, const int* in_sizes, int n_in,
                              void* d_out, int out_size, void* d_ws, size_t ws_size,
                              hipStream_t stream) {
    const int*   instructions   = (const int*)d_in[0];
    const float* hazard_weights = (const float*)d_in[5];

    float* dep   = (float*)d_out;                      // (B, W, W)
    float* ready = dep + (size_t)Bv * Wv * Wv;         // (B, W)

    // 2048 blocks x 4 waves = 8192 waves -> one b per wave, 8 blocks/CU
    // (full 32-wave occupancy), grid-stride for safety.
    ooo_kernel<<<2048, 256, 0, stream>>>(instructions, hazard_weights, dep, ready);
}

// Round 3
// 147.639 us; speedup vs baseline: 1.0370x; 1.0370x over previous
//
#include <hip/hip_runtime.h>

// NeuralOoOScheduler: B=8192, W=64. Embedding path in the reference is dead
// (del emb) — only the hazard dep_matrix + readiness are live.
// Pure streaming-write kernel: 134 MB dep + 2 MB ready out, 2 MB in.
//
// Wave-autonomous (no __syncthreads, no LDS). Each 64-lane wave owns one b.
// Column (j) operands and row (i) broadcasts come from __shfl of the raw
// instruction word; readiness reduced via __shfl_xor.
//
// R2 finding: __builtin_nontemporal_store regressed +7us vs cached stores
// (153.1 vs 146.2 total) — streaming writes WANT the L2/L3 path (the 6.4 TB/s
// fill kernel uses it). This round: same structure, plain float4 stores.

constexpr int Bv = 8192;
constexpr int Wv = 64;

__global__ __launch_bounds__(256) void ooo_kernel(
    const int* __restrict__ inst,
    const float* __restrict__ hw,
    float* __restrict__ dep,
    float* __restrict__ ready)
{
    const int lane  = threadIdx.x & 63;
    const int wid   = threadIdx.x >> 6;          // wave within block (0..3)
    const int wave0 = blockIdx.x * 4 + wid;      // global wave id
    const int nw    = gridDim.x * 4;

    // score = h0*raw + h2*waw + h4 -> only 4 distinct sigmoid values
    const float h0 = hw[0], h2 = hw[2], h4 = hw[4];
    const float v00 = 1.f / (1.f + __expf(-(h4)));            // raw=0 waw=0
    const float v10 = 1.f / (1.f + __expf(-(h0 + h4)));       // raw=1 waw=0
    const float v01 = 1.f / (1.f + __expf(-(h2 + h4)));       // raw=0 waw=1
    const float v11 = 1.f / (1.f + __expf(-(h0 + h2 + h4)));  // raw=1 waw=1

    // lane -> j in [jb, jb+4), i in {ig + 4k}; one wave-store per k covers
    // rows 4k..4k+3 = 1 KiB contiguous (lane l writes bytes 16l..16l+15).
    const int jb = (lane & 15) << 2;
    const int ig = lane >> 4;

    for (int b = wave0; b < Bv; b += nw) {
        const int v = inst[(size_t)b * Wv + lane];   // lane l holds inst[l]

        // column-j operands for this lane's j-quad, via wave shuffles
        int  rdj[4], rnj[4], rmj[4];
        bool jv[4];
#pragma unroll
        for (int q = 0; q < 4; ++q) {
            const int vj = __shfl(v, jb + q);
            rdj[q] = vj & 31;
            rnj[q] = (vj >> 5) & 31;
            rmj[q] = (vj >> 16) & 31;
            jv[q]  = rdj[q] < 31;
        }

        float prod[4] = {1.f, 1.f, 1.f, 1.f};
        float* const dep_row = dep + (size_t)b * (Wv * Wv);

#pragma unroll
        for (int k = 0; k < 16; ++k) {
            const int  i   = ig + 4 * k;
            const int  vi  = __shfl(v, i);      // broadcast row i's instruction
            const int  rdi = vi & 31;
            const bool iv  = rdi < 31;
            float o[4];
#pragma unroll
            for (int q = 0; q < 4; ++q) {
                const int  j   = jb + q;
                const bool raw = iv && ((rdi == rnj[q]) || (rdi == rmj[q]));
                const bool waw = iv && jv[q] && (rdi == rdj[q]);
                float val = waw ? (raw ? v11 : v01) : (raw ? v10 : v00);
                float d   = (j > i) ? val : 0.f;
                o[q] = d;
                prod[q] *= (1.f - d);
            }
            *(float4*)(dep_row + i * Wv + jb) =
                make_float4(o[0], o[1], o[2], o[3]);
        }

        // readiness[j] = product over the 4 lanes (ig=0..3) sharing this j-quad
#pragma unroll
        for (int q = 0; q < 4; ++q) {
            prod[q] *= __shfl_xor(prod[q], 16);
            prod[q] *= __shfl_xor(prod[q], 32);
        }
        if (ig == 0) {  // lanes 0..15 store 4 floats each -> 256 B contiguous
            *(float4*)(ready + (size_t)b * Wv + jb) =
                make_float4(prod[0], prod[1], prod[2], prod[3]);
        }
    }
}

extern "C" void kernel_launch(void* const* d_in, const int* in_sizes, int n_in,
                              void* d_out, int out_size, void* d_ws, size_t ws_size,
                              hipStream_t stream) {
    const int*   instructions   = (const int*)d_in[0];
    const float* hazard_weights = (const float*)d_in[5];

    float* dep   = (float*)d_out;                      // (B, W, W)
    float* ready = dep + (size_t)Bv * Wv * Wv;         // (B, W)

    // 2048 blocks x 4 waves = 8192 waves -> one b per wave, 8 blocks/CU
    // (full 32-wave occupancy), grid-stride for safety.
    ooo_kernel<<<2048, 256, 0, stream>>>(instructions, hazard_weights, dep, ready);
}